// Round 2
// baseline (1107.704 us; speedup 1.0000x reference)
//
#include <hip/hip_runtime.h>

#define DD 1024
#define HALO 32
#define IMG 1152               // floats per component image; 1152*4B = 9*512B
#define HALF_DT_F 0.05f
#define CG_ITERS_N 20

// XOR swizzle on float index: byte' = byte ^ (((byte>>7)&3)<<4).
// Involution; preserves 16B alignment; spreads 64B-lane-stride float4
// accesses across all 8 LDS bank groups. Commutes with offsets that are
// multiples of 128 floats (512B) -> IMG and row strides qualify.
__device__ __forceinline__ int swzf(int f) { return f ^ (((f >> 5) & 3) << 2); }

__device__ __forceinline__ void fence_lds() {
    asm volatile("s_waitcnt lgkmcnt(0)" ::: "memory");
}

__device__ __forceinline__ float wave_sum(float v) {
#pragma unroll
    for (int m = 32; m >= 1; m >>= 1)
        v += __shfl_xor(v, m, 64);
    return v;
}

// Store this lane's 16 elements (both components) to the swizzled row image,
// plus halo duplicates from edge lanes (lanes 0,1 -> right halo; 62,63 -> left).
__device__ __forceinline__ void store_row(float* lds, const int wa[4], const int ha[4],
                                          bool hh, const float vr[16], const float vi[16]) {
#pragma unroll
    for (int j = 0; j < 4; ++j) {
        float4 a = make_float4(vr[4 * j], vr[4 * j + 1], vr[4 * j + 2], vr[4 * j + 3]);
        float4 b = make_float4(vi[4 * j], vi[4 * j + 1], vi[4 * j + 2], vi[4 * j + 3]);
        *reinterpret_cast<float4*>(&lds[wa[j]]) = a;
        *reinterpret_cast<float4*>(&lds[wa[j] + IMG]) = b;
        if (hh) {
            *reinterpret_cast<float4*>(&lds[ha[j]]) = a;
            *reinterpret_cast<float4*>(&lds[ha[j] + IMG]) = b;
        }
    }
}

// H = diag(potential + 10*sum(w)) - sum_t cw[t]*(shift(+t)+shift(-t)) on this
// lane's 16 contiguous elements; reads a 56-float window as 14 swizzled float4s.
__device__ __forceinline__ void hmat16(const float* lds, const int ra[14], int cOff,
                                       const float cw[11], const float diag[16],
                                       float out[16]) {
    float win[56];
#pragma unroll
    for (int k = 0; k < 14; ++k) {
        float4 v = *reinterpret_cast<const float4*>(&lds[ra[k] + cOff]);
        win[4 * k + 0] = v.x;
        win[4 * k + 1] = v.y;
        win[4 * k + 2] = v.z;
        win[4 * k + 3] = v.w;
    }
    constexpr int taps[11] = {1, 2, 3, 4, 5, 6, 8, 10, 12, 16, 20};
#pragma unroll
    for (int i = 0; i < 16; ++i) {
        float acc = diag[i] * win[20 + i];
#pragma unroll
        for (int j = 0; j < 11; ++j)
            acc -= cw[j] * (win[20 + i - taps[j]] + win[20 + i + taps[j]]);
        out[i] = acc;
    }
}

__global__ void __launch_bounds__(256, 2)
cayley_kernel(const float* __restrict__ psi_r, const float* __restrict__ psi_i,
              const float* __restrict__ alpha, const float* __restrict__ sw,
              const float* __restrict__ potential, float* __restrict__ out) {
    __shared__ __align__(16) float lds[4 * 2 * IMG];

    const int t = threadIdx.x;
    const int l = t & 63;          // lane within wave; wave owns one row
    const int wv = t >> 6;
    const int row = (blockIdx.x << 2) + wv;
    const int base = wv * (2 * IMG);

    const float w0 = sw[0], w1 = sw[1], w2 = sw[2];
    const float cw[11] = {w0, w0 + w1, w0, w0 + w1 + w2, w0, w1, w1 + w2, w1, w2, w2, w2};
    const float dadd = 10.0f * (w0 + w1 + w2);

    // Loop-invariant swizzled LDS addresses (float indices, comp 0).
    int wa[4], ra[14];
#pragma unroll
    for (int j = 0; j < 4; ++j) wa[j] = swzf(base + HALO + 16 * l + 4 * j);
#pragma unroll
    for (int k = 0; k < 14; ++k) ra[k] = swzf(base + HALO - 20 + 16 * l + 4 * k);
    const bool hh = (l < 2) || (l >= 62);
    int ha[4] = {0, 0, 0, 0};
    if (l < 2) {
#pragma unroll
        for (int j = 0; j < 4; ++j) ha[j] = swzf(base + HALO + DD + 16 * l + 4 * j);
    } else if (l >= 62) {
#pragma unroll
        for (int j = 0; j < 4; ++j) ha[j] = swzf(base + HALO + 16 * l - DD + 4 * j);
    }

    // --- global loads: this lane's 16 contiguous elements ---
    const size_t goff = (size_t)row * DD + 16 * l;
    float prv[16], piv[16], alv[16], diag[16];
#pragma unroll
    for (int j = 0; j < 4; ++j) {
        float4 a = *reinterpret_cast<const float4*>(psi_r + goff + 4 * j);
        float4 b = *reinterpret_cast<const float4*>(psi_i + goff + 4 * j);
        float4 c = *reinterpret_cast<const float4*>(alpha + 16 * l + 4 * j);
        float4 d = *reinterpret_cast<const float4*>(potential + 16 * l + 4 * j);
        prv[4 * j] = a.x; prv[4 * j + 1] = a.y; prv[4 * j + 2] = a.z; prv[4 * j + 3] = a.w;
        piv[4 * j] = b.x; piv[4 * j + 1] = b.y; piv[4 * j + 2] = b.z; piv[4 * j + 3] = b.w;
        alv[4 * j] = c.x; alv[4 * j + 1] = c.y; alv[4 * j + 2] = c.z; alv[4 * j + 3] = c.w;
        diag[4 * j] = d.x + dadd; diag[4 * j + 1] = d.y + dadd;
        diag[4 * j + 2] = d.z + dadd; diag[4 * j + 3] = d.w + dadd;
    }

    // --- intensity + row mean (wave-local reduction) ---
    float inten[16];
    float isum = 0.f;
#pragma unroll
    for (int i = 0; i < 16; ++i) {
        inten[i] = prv[i] * prv[i] + piv[i] * piv[i];
        isum += inten[i];
    }
    const float tot = wave_sum(isum);
    const float inv_mean = 1.0f / (tot * (1.0f / DD) + 1e-8f);

    // --- nonlinear phase rotation ---
    float rotr[16], roti[16];
#pragma unroll
    for (int i = 0; i < 16; ++i) {
        const float ph = alv[i] * (inten[i] * inv_mean);
        float s, c;
        sincosf(ph, &s, &c);
        rotr[i] = prv[i] * c - piv[i] * s;
        roti[i] = prv[i] * s + piv[i] * c;
    }

    store_row(lds, wa, ha, hh, rotr, roti);
    fence_lds();

    // --- rhs = (I - i*dt/2*H) rot ---
    float Hr[16], Hi[16];
    hmat16(lds, ra, 0, cw, diag, Hr);
    hmat16(lds, ra, IMG, cw, diag, Hi);

    float xr[16], xi[16], rr[16], ri[16], pr_[16], pi_[16];
    float rsum = 0.f;
#pragma unroll
    for (int i = 0; i < 16; ++i) {
        xr[i] = 0.f; xi[i] = 0.f;
        rr[i] = rotr[i] + HALF_DT_F * Hi[i];
        ri[i] = roti[i] - HALF_DT_F * Hr[i];
        pr_[i] = rr[i]; pi_[i] = ri[i];
        rsum += rr[i] * rr[i] + ri[i] * ri[i];
    }
    float rs = wave_sum(rsum);

    store_row(lds, wa, ha, hh, pr_, pi_);
    fence_lds();

    // --- CG: 20 fixed iterations, fully wave-local ---
    for (int it = 0; it < CG_ITERS_N; ++it) {
        hmat16(lds, ra, 0, cw, diag, Hr);
        hmat16(lds, ra, IMG, cw, diag, Hi);
        float Apr[16], Api[16];
        float pap = 0.f;
#pragma unroll
        for (int i = 0; i < 16; ++i) {
            Apr[i] = pr_[i] - HALF_DT_F * Hi[i];
            Api[i] = pi_[i] + HALF_DT_F * Hr[i];
            pap += pr_[i] * Apr[i] + pi_[i] * Api[i];
        }
        const float pAp = wave_sum(pap);
        const float alr = rs / (pAp + 1e-12f);
        float rnew = 0.f;
#pragma unroll
        for (int i = 0; i < 16; ++i) {
            xr[i] += alr * pr_[i];
            xi[i] += alr * pi_[i];
            rr[i] -= alr * Apr[i];
            ri[i] -= alr * Api[i];
            rnew += rr[i] * rr[i] + ri[i] * ri[i];
        }
        const float rs_new = wave_sum(rnew);
        const float beta = rs_new / (rs + 1e-12f);
        rs = rs_new;
#pragma unroll
        for (int i = 0; i < 16; ++i) {
            pr_[i] = rr[i] + beta * pr_[i];
            pi_[i] = ri[i] + beta * pi_[i];
        }
        store_row(lds, wa, ha, hh, pr_, pi_);
        fence_lds();
    }

    // --- write x as [.., D, 2] real pairs ---
    float* op = out + 2 * goff;
#pragma unroll
    for (int j = 0; j < 8; ++j) {
        *reinterpret_cast<float4*>(op + 4 * j) =
            make_float4(xr[2 * j], xi[2 * j], xr[2 * j + 1], xi[2 * j + 1]);
    }
}

extern "C" void kernel_launch(void* const* d_in, const int* in_sizes, int n_in,
                              void* d_out, int out_size, void* d_ws, size_t ws_size,
                              hipStream_t stream) {
    const float* psi_r = (const float*)d_in[0];
    const float* psi_i = (const float*)d_in[1];
    const float* alpha = (const float*)d_in[2];
    const float* sw = (const float*)d_in[3];
    const float* pot = (const float*)d_in[4];
    float* out = (float*)d_out;
    const int rows = in_sizes[0] / DD;   // B*S = 8192
    cayley_kernel<<<dim3(rows / 4), dim3(256), 0, stream>>>(psi_r, psi_i, alpha, sw, pot, out);
}